// Round 9
// baseline (154.603 us; speedup 1.0000x reference)
//
#include <hip/hip_runtime.h>
#include <hip/hip_bf16.h>

#define B_   4
#define LQ_  900
#define D_   256
#define NH_  8
#define DH_  32
#define NL_  4
#define NP_  4
#define DFF_ 1024
#define LIN_ 21760
#define MQ_  (LQ_*B_)    // 3600
#define MV_  (LIN_*B_)   // 87040

typedef __attribute__((ext_vector_type(8))) short bh8;
typedef __attribute__((ext_vector_type(4))) float f32x4;

__device__ __forceinline__ short bf16b(float f) {
    __hip_bfloat16 h = __float2bfloat16(f);
    return *reinterpret_cast<short*>(&h);
}

__device__ __forceinline__ bh8 af_from_f32(const float* p) {
    float4 v0 = *reinterpret_cast<const float4*>(p);
    float4 v1 = *reinterpret_cast<const float4*>(p + 4);
    return (bh8){ bf16b(v0.x), bf16b(v0.y), bf16b(v0.z), bf16b(v0.w),
                  bf16b(v1.x), bf16b(v1.y), bf16b(v1.z), bf16b(v1.w) };
}

// ---- all weights -> MFMA B-frag images ----
// image block (ntile, kq): 1 KB; byte (g*16+n16)*16 + j*2 = W[ntile*16+n16][kq*32+g*8+j]
__global__ __launch_bounds__(256)
void wprep_k(const float* __restrict__ Woff, const float* __restrict__ Wattn,
             const float* __restrict__ Wout, const float* __restrict__ W1,
             const float* __restrict__ W2, const float* __restrict__ Wval,
             unsigned char* __restrict__ qkvimg, unsigned char* __restrict__ outimg,
             unsigned char* __restrict__ w1img, unsigned char* __restrict__ w2img,
             unsigned char* __restrict__ valimg)
{
    const int cid = blockIdx.x*256 + threadIdx.x;   // 94208 total
    const float* W; unsigned char* img; int KQ, c;
    if      (cid < 8192)  { W=Woff;  img=qkvimg;           KQ=8;  c=cid;       }
    else if (cid < 12288) { W=Wattn; img=qkvimg + 131072;  KQ=8;  c=cid-8192;  }
    else if (cid < 20480) { W=Wout;  img=outimg;           KQ=8;  c=cid-12288; }
    else if (cid < 53248) { W=W1;    img=w1img;            KQ=8;  c=cid-20480; }
    else if (cid < 86016) { W=W2;    img=w2img;            KQ=32; c=cid-53248; }
    else                  { W=Wval;  img=valimg;           KQ=8;  c=cid-86016; }
    const int K   = KQ*32;
    const int n16 = c & 15, g = (c>>4)&3, t = c>>6;
    const int kq  = t & (KQ-1);
    const int ntile = t >> ((KQ==8) ? 3 : 5);
    const int n = ntile*16 + n16, k0 = kq*32 + g*8;
    float4 v0 = *reinterpret_cast<const float4*>(&W[(size_t)n*K + k0]);
    float4 v1 = *reinterpret_cast<const float4*>(&W[(size_t)n*K + k0 + 4]);
    union { short s[8]; uint4 u; } pk;
    pk.s[0]=bf16b(v0.x); pk.s[1]=bf16b(v0.y); pk.s[2]=bf16b(v0.z); pk.s[3]=bf16b(v0.w);
    pk.s[4]=bf16b(v1.x); pk.s[5]=bf16b(v1.y); pk.s[6]=bf16b(v1.z); pk.s[7]=bf16b(v1.w);
    *reinterpret_cast<uint4*>(img + (size_t)(ntile*KQ + kq)*1024 + (g*16+n16)*16) = pk.u;
}

// ---------------- value GEMM v3: barrier-free, LDS-free, A-frags direct ----------------
// M-tile 64, 512 thr (8 waves: 2 wave-rows x 4 wave-cols), W from B-frag image (L2).
__global__ __launch_bounds__(512)
void val_gemm_k(const float* __restrict__ A, const unsigned char* __restrict__ Wimg,
                const float* __restrict__ bias, unsigned short* __restrict__ C,
                const unsigned char* __restrict__ mask)
{
    const int tid  = threadIdx.x;
    const int lane = tid & 63;
    const int wid  = tid >> 6;
    const int wr   = wid >> 2;     // 0..1
    const int wc   = wid & 3;      // 0..3
    const int m16  = lane & 15;
    const int g    = lane >> 4;
    const int m0   = blockIdx.x * 64;

    const float* arow[2];
    #pragma unroll
    for (int mf = 0; mf < 2; ++mf)
        arow[mf] = A + (size_t)(m0 + wr*32 + mf*16 + m16)*256 + g*8;

    f32x4 acc[2][4];
    #pragma unroll
    for (int i = 0; i < 2; ++i)
        #pragma unroll
        for (int j = 0; j < 4; ++j) acc[i][j] = (f32x4){0.f,0.f,0.f,0.f};

    #pragma unroll
    for (int kq = 0; kq < 8; ++kq) {
        bh8 af[2];
        #pragma unroll
        for (int mf = 0; mf < 2; ++mf)
            af[mf] = af_from_f32(arow[mf] + kq*32);
        bh8 bf[4];
        #pragma unroll
        for (int i = 0; i < 4; ++i) {
            const int nt = wc*4 + i;
            bf[i] = *reinterpret_cast<const bh8*>(Wimg + (size_t)(nt*8 + kq)*1024 + lane*16);
        }
        #pragma unroll
        for (int mf = 0; mf < 2; ++mf)
            #pragma unroll
            for (int i = 0; i < 4; ++i)
                acc[mf][i] = __builtin_amdgcn_mfma_f32_16x16x32_bf16(af[mf], bf[i], acc[mf][i], 0, 0, 0);
    }

    float bv[4];
    #pragma unroll
    for (int i = 0; i < 4; ++i) bv[i] = bias[wc*64 + i*16 + m16];

    #pragma unroll
    for (int mf = 0; mf < 2; ++mf) {
        #pragma unroll
        for (int r = 0; r < 4; ++r) {
            const int gm = m0 + wr*32 + mf*16 + g*4 + r;
            const bool z = mask[(gm & 3)*LIN_ + (gm >> 2)] != 0;
            #pragma unroll
            for (int i = 0; i < 4; ++i) {
                float v = acc[mf][i][r] + bv[i];
                if (z) v = 0.f;
                C[(size_t)gm*256 + wc*64 + i*16 + m16] = (unsigned short)bf16b(v);
            }
        }
    }
}

// ---------------- fused off+attn projections ----------------
__global__ __launch_bounds__(512)
void qkv_k(const float* __restrict__ A, const unsigned char* __restrict__ Wimg,
           const float* __restrict__ b_off, const float* __restrict__ b_attn,
           float* __restrict__ Yoff, float* __restrict__ Yattn)
{
    const int tid = threadIdx.x, lane = tid & 63, w = tid >> 6;
    const int m16 = lane & 15, g = lane >> 4;
    const int m0 = blockIdx.x * 16;

    bh8 af[8];
    #pragma unroll
    for (int kq = 0; kq < 8; ++kq)
        af[kq] = af_from_f32(&A[(size_t)(m0 + m16)*256 + kq*32 + g*8]);

    f32x4 acc[3];
    #pragma unroll
    for (int i = 0; i < 3; ++i) acc[i] = (f32x4){0.f,0.f,0.f,0.f};

    #pragma unroll
    for (int i = 0; i < 3; ++i) {
        const int nt = w*3 + i;
        #pragma unroll
        for (int kq = 0; kq < 8; ++kq) {
            bh8 bf = *reinterpret_cast<const bh8*>(Wimg + (size_t)(nt*8 + kq)*1024 + lane*16);
            acc[i] = __builtin_amdgcn_mfma_f32_16x16x32_bf16(af[kq], bf, acc[i], 0, 0, 0);
        }
    }

    #pragma unroll
    for (int i = 0; i < 3; ++i) {
        const int nt = w*3 + i;
        const int j  = nt*16 + m16;
        #pragma unroll
        for (int r = 0; r < 4; ++r) {
            const int m = m0 + g*4 + r;
            if (nt < 16) Yoff[(size_t)m*256 + j] = acc[i][r] + b_off[j];
            else         Yattn[(size_t)m*128 + (j-256)] = acc[i][r] + b_attn[j-256];
        }
    }
}

// ---------------- out-proj + add-tgt + LN1 fused -> tb ----------------
__global__ __launch_bounds__(512)
void outln_k(const float* __restrict__ A, const unsigned char* __restrict__ Wimg,
             const float* __restrict__ bias, const float* __restrict__ res,
             const float* __restrict__ lg, const float* __restrict__ lb,
             float* __restrict__ T)
{
    __shared__ float sln[16][256];

    const int tid = threadIdx.x, lane = tid & 63, w = tid >> 6;
    const int m16 = lane & 15, g = lane >> 4;
    const int m0 = blockIdx.x * 16;

    bh8 af[8];
    #pragma unroll
    for (int kq = 0; kq < 8; ++kq)
        af[kq] = af_from_f32(&A[(size_t)(m0 + m16)*256 + kq*32 + g*8]);

    f32x4 acc[2];
    acc[0] = (f32x4){0.f,0.f,0.f,0.f};
    acc[1] = (f32x4){0.f,0.f,0.f,0.f};

    #pragma unroll
    for (int i = 0; i < 2; ++i) {
        const int nt = w*2 + i;
        #pragma unroll
        for (int kq = 0; kq < 8; ++kq) {
            bh8 bf = *reinterpret_cast<const bh8*>(Wimg + (size_t)(nt*8 + kq)*1024 + lane*16);
            acc[i] = __builtin_amdgcn_mfma_f32_16x16x32_bf16(af[kq], bf, acc[i], 0, 0, 0);
        }
    }

    #pragma unroll
    for (int i = 0; i < 2; ++i) {
        const int nt = w*2 + i;
        const int j  = nt*16 + m16;
        #pragma unroll
        for (int r = 0; r < 4; ++r) {
            const int ml = g*4 + r;
            sln[ml][j] = acc[i][r] + bias[j] + res[(size_t)(m0 + ml)*256 + j];
        }
    }
    __syncthreads();

    const int row = tid >> 5, l2 = tid & 31;
    float v[8], s1 = 0.f, s2 = 0.f;
    #pragma unroll
    for (int c = 0; c < 8; ++c) {
        v[c] = sln[row][l2 + c*32];
        s1 += v[c]; s2 += v[c]*v[c];
    }
    #pragma unroll
    for (int o = 16; o >= 1; o >>= 1) {
        s1 += __shfl_xor(s1, o, 64);
        s2 += __shfl_xor(s2, o, 64);
    }
    const float mu  = s1 * (1.f/256.f);
    const float var = s2 * (1.f/256.f) - mu*mu;
    const float is  = rsqrtf(var + 1e-5f);
    #pragma unroll
    for (int c = 0; c < 8; ++c) {
        const int j = l2 + c*32;
        T[(size_t)(m0 + row)*256 + j] = (v[c] - mu) * is * lg[j] + lb[j];
    }
}

// ---------------- fused FFN (f-split 4) ----------------
__global__ __launch_bounds__(512)
void ffn_k(const float* __restrict__ T, const unsigned char* __restrict__ W1img,
           const float* __restrict__ b1, const unsigned char* __restrict__ W2img,
           const float* __restrict__ b2, float* __restrict__ Y)
{
    __shared__ __align__(16) short hl[2][32*72];

    const int tid = threadIdx.x, lane = tid & 63, w = tid >> 6;
    const int m16 = lane & 15, g = lane >> 4;
    const int mt = w & 1, wn = w >> 1;
    const int m0 = blockIdx.x * 32;
    const int fg = blockIdx.y;

    bh8 af1[8];
    #pragma unroll
    for (int kq = 0; kq < 8; ++kq) {
        int gm = m0 + mt*16 + m16; if (gm > MQ_-1) gm = MQ_-1;
        af1[kq] = af_from_f32(&T[(size_t)gm*256 + kq*32 + g*8]);
    }

    f32x4 yacc[4];
    #pragma unroll
    for (int i = 0; i < 4; ++i) yacc[i] = (f32x4){0.f,0.f,0.f,0.f};

    int buf = 0;
    #pragma unroll
    for (int fc = 0; fc < 4; ++fc) {
        const int ftile_g = fg*16 + fc*4 + wn;
        f32x4 hacc = (f32x4){0.f,0.f,0.f,0.f};
        #pragma unroll
        for (int kq = 0; kq < 8; ++kq) {
            bh8 bf = *reinterpret_cast<const bh8*>(W1img + (size_t)(ftile_g*8 + kq)*1024 + lane*16);
            hacc = __builtin_amdgcn_mfma_f32_16x16x32_bf16(af1[kq], bf, hacc, 0, 0, 0);
        }
        const float bb = b1[ftile_g*16 + m16];
        #pragma unroll
        for (int r = 0; r < 4; ++r) {
            const float v = fmaxf(hacc[r] + bb, 0.f);
            *reinterpret_cast<short*>((char*)&hl[buf][0]
                + (mt*16 + g*4 + r)*144 + (wn*16 + m16)*2) = bf16b(v);
        }
        __syncthreads();
        bh8 a2[2];
        #pragma unroll
        for (int kqf = 0; kqf < 2; ++kqf)
            a2[kqf] = *reinterpret_cast<const bh8*>((char*)&hl[buf][0]
                + (mt*16 + m16)*144 + (kqf*32 + g*8)*2);
        #pragma unroll
        for (int i = 0; i < 4; ++i) {
            const int nt = wn*4 + i;
            #pragma unroll
            for (int kqf = 0; kqf < 2; ++kqf) {
                const int kq2 = fg*8 + fc*2 + kqf;
                bh8 bf = *reinterpret_cast<const bh8*>(W2img + (size_t)(nt*32 + kq2)*1024 + lane*16);
                yacc[i] = __builtin_amdgcn_mfma_f32_16x16x32_bf16(a2[kqf], bf, yacc[i], 0, 0, 0);
            }
        }
        buf ^= 1;
    }

    float* Yg = Y + (size_t)fg*MQ_*256;
    #pragma unroll
    for (int i = 0; i < 4; ++i) {
        const int j = (wn*4 + i)*16 + m16;
        const float b2v = (fg == 0) ? b2[j] : 0.f;
        #pragma unroll
        for (int r = 0; r < 4; ++r) {
            const int m = m0 + mt*16 + g*4 + r;
            if (m < MQ_) Yg[(size_t)m*256 + j] = yacc[i][r] + b2v;
        }
    }
}

// ---------------- deformable sampling ----------------
__global__ __launch_bounds__(256)
void msda_k(const float* __restrict__ off,
            const float* __restrict__ attnlog,
            const float* __restrict__ refp,
            const __hip_bfloat16* __restrict__ value,
            float* __restrict__ out)
{
    const int m = blockIdx.x;
    const int b = m & 3;
    const int d = threadIdx.x;
    const int h = d >> 5;

    __shared__ float s_off[256];
    __shared__ float s_al[128];
    __shared__ float s_ref[NL_*2];
    s_off[d] = off[(size_t)m*256 + d];
    if (d < 128) s_al[d] = attnlog[(size_t)m*128 + d];
    if (d < NL_*2) s_ref[d] = refp[(size_t)m*(NL_*2) + d];
    __syncthreads();

    float mx = -1e30f;
    #pragma unroll
    for (int t = 0; t < 16; ++t) mx = fmaxf(mx, s_al[h*16 + t]);
    float e[16], ssum = 0.f;
    #pragma unroll
    for (int t = 0; t < 16; ++t) { e[t] = __expf(s_al[h*16 + t] - mx); ssum += e[t]; }
    const float inv = 1.f / ssum;

    const int HS[4] = {128, 64, 32, 16};
    const int ST[4] = {0, 16384, 20480, 21504};

    float acc = 0.f;
    #pragma unroll
    for (int l = 0; l < NL_; ++l) {
        const int H = HS[l], W = HS[l], st = ST[l];
        const float rx = s_ref[l*2+0], ry = s_ref[l*2+1];
        #pragma unroll
        for (int p = 0; p < NP_; ++p) {
            const int base = ((h*NL_ + l)*NP_ + p);
            const float a  = e[l*4 + p] * inv;
            const float ox = s_off[base*2+0], oy = s_off[base*2+1];
            const float x = rx*(float)W + ox - 0.5f;
            const float y = ry*(float)H + oy - 0.5f;
            const float x0f = floorf(x), y0f = floorf(y);
            const int x0 = (int)x0f, y0 = (int)y0f;
            const float wx1 = x - x0f, wy1 = y - y0f;
            const float wx0 = 1.f - wx1, wy0 = 1.f - wy1;
            #pragma unroll
            for (int t = 0; t < 4; ++t) {
                const int xi = x0 + (t & 1);
                const int yi = y0 + (t >> 1);
                const float wgt = (t==0 ? wx0*wy0 : t==1 ? wx1*wy0 : t==2 ? wx0*wy1 : wx1*wy1);
                if (xi >= 0 && xi < W && yi >= 0 && yi < H) {
                    const size_t idx = (size_t)(st + yi*W + xi);
                    const float v = __bfloat162float(value[(idx*B_ + b)*D_ + d]);
                    acc = fmaf(a*wgt, v, acc);
                }
            }
        }
    }
    out[(size_t)m*256 + d] = acc;
}

// ---- final LN: out = LN(t + y0+y1+y2+y3) ----
__global__ __launch_bounds__(256)
void add_ln4_k(const float* __restrict__ yp, const float* __restrict__ r,
               const float* __restrict__ g, const float* __restrict__ be,
               float* __restrict__ out)
{
    const int m = blockIdx.x, d = threadIdx.x;
    const size_t S = (size_t)MQ_*256, o = (size_t)m*D_ + d;
    const float v = r[o] + yp[o] + yp[S+o] + yp[2*S+o] + yp[3*S+o];
    float s1 = v, s2 = v*v;
    #pragma unroll
    for (int of = 32; of >= 1; of >>= 1) {
        s1 += __shfl_xor(s1, of, 64);
        s2 += __shfl_xor(s2, of, 64);
    }
    __shared__ float r1[4], r2[4];
    const int w = d >> 6;
    if ((d & 63) == 0) { r1[w] = s1; r2[w] = s2; }
    __syncthreads();
    const float t1 = r1[0]+r1[1]+r1[2]+r1[3];
    const float t2 = r2[0]+r2[1]+r2[2]+r2[3];
    const float mu  = t1 * (1.f/D_);
    const float var = t2 * (1.f/D_) - mu*mu;
    const float is  = rsqrtf(var + 1e-5f);
    out[o] = (v - mu) * is * g[d] + be[d];
}

extern "C" void kernel_launch(void* const* d_in, const int* in_sizes, int n_in,
                              void* d_out, int out_size, void* d_ws, size_t ws_size,
                              hipStream_t stream)
{
    const float* tgt    = (const float*)d_in[0];
    const float* refp   = (const float*)d_in[1];
    const float* mem    = (const float*)d_in[2];
    const float* W_off  = (const float*)d_in[3];
    const float* b_off  = (const float*)d_in[4];
    const float* W_attn = (const float*)d_in[5];
    const float* b_attn = (const float*)d_in[6];
    const float* W_val  = (const float*)d_in[7];
    const float* b_val  = (const float*)d_in[8];
    const float* W_out  = (const float*)d_in[9];
    const float* b_out  = (const float*)d_in[10];
    const float* ln1g   = (const float*)d_in[11];
    const float* ln1b   = (const float*)d_in[12];
    const float* W1     = (const float*)d_in[13];
    const float* b1     = (const float*)d_in[14];
    const float* W2     = (const float*)d_in[15];
    const float* b2     = (const float*)d_in[16];
    const float* ln3g   = (const float*)d_in[17];
    const float* ln3b   = (const float*)d_in[18];
    const unsigned char* mask = (const unsigned char*)d_in[21];
    float* out = (float*)d_out;

    char* p = (char*)d_ws;
    __hip_bfloat16* value = (__hip_bfloat16*)p; p += (size_t)MV_*D_*2;   // 44.6 MB
    float* offb = (float*)p; p += (size_t)MQ_*256*4;
    float* attl = (float*)p; p += (size_t)MQ_*128*4;
    float* msda = (float*)p; p += (size_t)MQ_*256*4;
    float* tb   = (float*)p; p += (size_t)MQ_*256*4;
    float* ypart= (float*)p; p += (size_t)4*MQ_*256*4;                   // 14.7 MB
    unsigned char* qkvimg = (unsigned char*)p; p += 196608;
    unsigned char* outimg = (unsigned char*)p; p += 131072;
    unsigned char* w1img  = (unsigned char*)p; p += 524288;
    unsigned char* w2img  = (unsigned char*)p; p += 524288;
    unsigned char* valimg = (unsigned char*)p; p += 131072;
    (void)ws_size; (void)in_sizes; (void)n_in; (void)out_size;

    // 0) weight B-frag images (incl. W_val)
    wprep_k<<<dim3(368), dim3(256), 0, stream>>>(W_off, W_attn, W_out, W1, W2, W_val,
                                                 qkvimg, outimg, w1img, w2img, valimg);
    // 1) value projection: barrier-free, LDS-free MFMA
    val_gemm_k<<<dim3(MV_/64), dim3(512), 0, stream>>>(mem, valimg, b_val,
                                                       (unsigned short*)value, mask);
    // 2+3) off + attn logits, fused
    qkv_k<<<dim3(MQ_/16), dim3(512), 0, stream>>>(tgt, qkvimg, b_off, b_attn, offb, attl);
    // 4) deformable sampling
    msda_k<<<dim3(MQ_), dim3(256), 0, stream>>>(offb, attl, refp, value, msda);
    // 5+6) ca = msda @ W_out^T + b_out ; tb = LN(tgt + ca)   (fused)
    outln_k<<<dim3(MQ_/16), dim3(512), 0, stream>>>(msda, outimg, b_out, tgt, ln1g, ln1b, tb);
    // 7+8) FFN fused, f-split x4
    ffn_k<<<dim3((MQ_+31)/32, 4), dim3(512), 0, stream>>>(tb, w1img, b1, w2img, b2, ypart);
    // 9) out = LN(t + sum(y-partials))
    add_ln4_k<<<dim3(MQ_), dim3(256), 0, stream>>>(ypart, tb, ln3g, ln3b, out);
}

// Round 10
// 124.807 us; speedup vs baseline: 1.2387x; 1.2387x over previous
//
#include <hip/hip_runtime.h>
#include <hip/hip_bf16.h>

#define B_   4
#define LQ_  900
#define D_   256
#define NH_  8
#define DH_  32
#define NL_  4
#define NP_  4
#define DFF_ 1024
#define LIN_ 21760
#define MQ_  (LQ_*B_)    // 3600
#define MV_  (LIN_*B_)   // 87040

typedef __attribute__((ext_vector_type(8))) short bh8;
typedef __attribute__((ext_vector_type(4))) float f32x4;

__device__ __forceinline__ short bf16b(float f) {
    __hip_bfloat16 h = __float2bfloat16(f);
    return *reinterpret_cast<short*>(&h);
}

__device__ __forceinline__ void gload_lds16(const void* g, void* l) {
    __builtin_amdgcn_global_load_lds(
        (const __attribute__((address_space(1))) unsigned int*)g,
        (__attribute__((address_space(3))) unsigned int*)l, 16, 0, 0);
}

__device__ __forceinline__ bh8 af_from_f32(const float* p) {
    float4 v0 = *reinterpret_cast<const float4*>(p);
    float4 v1 = *reinterpret_cast<const float4*>(p + 4);
    return (bh8){ bf16b(v0.x), bf16b(v0.y), bf16b(v0.z), bf16b(v0.w),
                  bf16b(v1.x), bf16b(v1.y), bf16b(v1.z), bf16b(v1.w) };
}

// ---- all weights -> MFMA B-frag images ----
// image block (ntile, kq): 1 KB; byte (g*16+n16)*16 + j*2 = W[ntile*16+n16][kq*32+g*8+j]
__global__ __launch_bounds__(256)
void wprep_k(const float* __restrict__ Woff, const float* __restrict__ Wattn,
             const float* __restrict__ Wout, const float* __restrict__ W1,
             const float* __restrict__ W2, const float* __restrict__ Wval,
             unsigned char* __restrict__ qkvimg, unsigned char* __restrict__ outimg,
             unsigned char* __restrict__ w1img, unsigned char* __restrict__ w2img,
             unsigned char* __restrict__ valimg)
{
    const int cid = blockIdx.x*256 + threadIdx.x;   // 94208 total
    const float* W; unsigned char* img; int KQ, c;
    if      (cid < 8192)  { W=Woff;  img=qkvimg;           KQ=8;  c=cid;       }
    else if (cid < 12288) { W=Wattn; img=qkvimg + 131072;  KQ=8;  c=cid-8192;  }
    else if (cid < 20480) { W=Wout;  img=outimg;           KQ=8;  c=cid-12288; }
    else if (cid < 53248) { W=W1;    img=w1img;            KQ=8;  c=cid-20480; }
    else if (cid < 86016) { W=W2;    img=w2img;            KQ=32; c=cid-53248; }
    else                  { W=Wval;  img=valimg;           KQ=8;  c=cid-86016; }
    const int K   = KQ*32;
    const int n16 = c & 15, g = (c>>4)&3, t = c>>6;
    const int kq  = t & (KQ-1);
    const int ntile = t >> ((KQ==8) ? 3 : 5);
    const int n = ntile*16 + n16, k0 = kq*32 + g*8;
    float4 v0 = *reinterpret_cast<const float4*>(&W[(size_t)n*K + k0]);
    float4 v1 = *reinterpret_cast<const float4*>(&W[(size_t)n*K + k0 + 4]);
    union { short s[8]; uint4 u; } pk;
    pk.s[0]=bf16b(v0.x); pk.s[1]=bf16b(v0.y); pk.s[2]=bf16b(v0.z); pk.s[3]=bf16b(v0.w);
    pk.s[4]=bf16b(v1.x); pk.s[5]=bf16b(v1.y); pk.s[6]=bf16b(v1.z); pk.s[7]=bf16b(v1.w);
    *reinterpret_cast<uint4*>(img + (size_t)(ntile*KQ + kq)*1024 + (g*16+n16)*16) = pk.u;
}

// ---------------- value GEMM v4: 2-phase software pipeline, raw barriers ----------------
// 128x256 tile, BK=32, 8 K-steps, named double buffers, counted-drain sync.
// A fp32 staged via pre-swizzled-source global_load_lds; W from B-frag image (linear).
__global__ __launch_bounds__(512, 4)
void val_gemm_k(const float* __restrict__ A, const unsigned char* __restrict__ Wimg,
                const float* __restrict__ bias, unsigned short* __restrict__ C,
                const unsigned char* __restrict__ mask)
{
    __shared__ __align__(16) unsigned char A0[16384];
    __shared__ __align__(16) unsigned char A1[16384];
    __shared__ __align__(16) unsigned char W0[16384];
    __shared__ __align__(16) unsigned char W1[16384];

    const int tid  = threadIdx.x;
    const int lane = tid & 63;
    const int wid  = tid >> 6;
    const int wr   = wid >> 2;     // 0..1
    const int wc   = wid & 3;      // 0..3
    const int m0   = blockIdx.x * 128;
    const int r16  = lane & 15;
    const int g    = lane >> 4;

    const unsigned char* Abyte = (const unsigned char*)A;

    f32x4 acc[4][4];
    #pragma unroll
    for (int i = 0; i < 4; ++i)
        #pragma unroll
        for (int j = 0; j < 4; ++j) acc[i][j] = (f32x4){0.f,0.f,0.f,0.f};

#define STAGE(Ab, Wb, KT) do {                                                          \
    _Pragma("unroll")                                                                   \
    for (int ps = 0; ps < 2; ++ps) {                                                    \
        const int off = ps*8192 + tid*16;                                               \
        const int row = off >> 7;                                                       \
        const int x   = off & 127;                                                      \
        gload_lds16(Abyte + (size_t)(m0+row)*1024 + (KT)*128 + (x ^ ((row&7)<<4)),      \
                    (char*)(Ab) + off);                                                 \
        const int nt  = off >> 10;                                                      \
        const int inn = off & 1023;                                                     \
        gload_lds16(Wimg + (size_t)(nt*8 + (KT))*1024 + inn, (char*)(Wb) + off);        \
    }                                                                                   \
} while (0)

#define COMPUTE(Ab, Wb) do {                                                            \
    bh8 af[4], bf[4];                                                                   \
    _Pragma("unroll")                                                                   \
    for (int mf = 0; mf < 4; ++mf) {                                                    \
        const int row = wr*64 + mf*16 + r16;                                            \
        const int swz = (row & 7) << 4;                                                 \
        float4 v0 = *reinterpret_cast<const float4*>((const char*)(Ab) + row*128 + ((g*32     ) ^ swz)); \
        float4 v1 = *reinterpret_cast<const float4*>((const char*)(Ab) + row*128 + ((g*32 + 16) ^ swz)); \
        af[mf] = (bh8){ bf16b(v0.x), bf16b(v0.y), bf16b(v0.z), bf16b(v0.w),             \
                        bf16b(v1.x), bf16b(v1.y), bf16b(v1.z), bf16b(v1.w) };           \
    }                                                                                   \
    _Pragma("unroll")                                                                   \
    for (int i = 0; i < 4; ++i)                                                         \
        bf[i] = *reinterpret_cast<const bh8*>((const char*)(Wb) + (wc*4+i)*1024 + lane*16); \
    _Pragma("unroll")                                                                   \
    for (int mf = 0; mf < 4; ++mf)                                                      \
        _Pragma("unroll")                                                               \
        for (int i = 0; i < 4; ++i)                                                     \
            acc[mf][i] = __builtin_amdgcn_mfma_f32_16x16x32_bf16(af[mf], bf[i], acc[mf][i], 0, 0, 0); \
} while (0)

    // prologue
    STAGE(A0, W0, 0);
    asm volatile("s_waitcnt vmcnt(0)" ::: "memory");
    __builtin_amdgcn_s_barrier();

    #pragma unroll
    for (int kt2 = 0; kt2 < 4; ++kt2) {
        // phase A: prefetch odd chunk, compute even chunk
        STAGE(A1, W1, 2*kt2 + 1);
        COMPUTE(A0, W0);
        asm volatile("s_waitcnt vmcnt(0)" ::: "memory");
        __builtin_amdgcn_s_barrier();
        // phase B: prefetch next even chunk, compute odd chunk
        if (kt2 < 3) STAGE(A0, W0, 2*kt2 + 2);
        COMPUTE(A1, W1);
        asm volatile("s_waitcnt vmcnt(0)" ::: "memory");
        __builtin_amdgcn_s_barrier();
    }
#undef STAGE
#undef COMPUTE

    float bv[4];
    #pragma unroll
    for (int nf = 0; nf < 4; ++nf) bv[nf] = bias[wc*64 + nf*16 + r16];

    #pragma unroll
    for (int mf = 0; mf < 4; ++mf) {
        #pragma unroll
        for (int r = 0; r < 4; ++r) {
            const int gm = m0 + wr*64 + mf*16 + g*4 + r;
            const bool z = mask[(gm & 3)*LIN_ + (gm >> 2)] != 0;
            #pragma unroll
            for (int nf = 0; nf < 4; ++nf) {
                float v = acc[mf][nf][r] + bv[nf];
                if (z) v = 0.f;
                C[(size_t)gm*256 + wc*64 + nf*16 + r16] = (unsigned short)bf16b(v);
            }
        }
    }
}

// ---------------- fused off+attn projections ----------------
__global__ __launch_bounds__(512)
void qkv_k(const float* __restrict__ A, const unsigned char* __restrict__ Wimg,
           const float* __restrict__ b_off, const float* __restrict__ b_attn,
           float* __restrict__ Yoff, float* __restrict__ Yattn)
{
    const int tid = threadIdx.x, lane = tid & 63, w = tid >> 6;
    const int m16 = lane & 15, g = lane >> 4;
    const int m0 = blockIdx.x * 16;

    bh8 af[8];
    #pragma unroll
    for (int kq = 0; kq < 8; ++kq)
        af[kq] = af_from_f32(&A[(size_t)(m0 + m16)*256 + kq*32 + g*8]);

    f32x4 acc[3];
    #pragma unroll
    for (int i = 0; i < 3; ++i) acc[i] = (f32x4){0.f,0.f,0.f,0.f};

    #pragma unroll
    for (int i = 0; i < 3; ++i) {
        const int nt = w*3 + i;
        #pragma unroll
        for (int kq = 0; kq < 8; ++kq) {
            bh8 bf = *reinterpret_cast<const bh8*>(Wimg + (size_t)(nt*8 + kq)*1024 + lane*16);
            acc[i] = __builtin_amdgcn_mfma_f32_16x16x32_bf16(af[kq], bf, acc[i], 0, 0, 0);
        }
    }

    #pragma unroll
    for (int i = 0; i < 3; ++i) {
        const int nt = w*3 + i;
        const int j  = nt*16 + m16;
        #pragma unroll
        for (int r = 0; r < 4; ++r) {
            const int m = m0 + g*4 + r;
            if (nt < 16) Yoff[(size_t)m*256 + j] = acc[i][r] + b_off[j];
            else         Yattn[(size_t)m*128 + (j-256)] = acc[i][r] + b_attn[j-256];
        }
    }
}

// ---------------- out-proj + add-tgt + LN1 fused -> tb ----------------
__global__ __launch_bounds__(512)
void outln_k(const float* __restrict__ A, const unsigned char* __restrict__ Wimg,
             const float* __restrict__ bias, const float* __restrict__ res,
             const float* __restrict__ lg, const float* __restrict__ lb,
             float* __restrict__ T)
{
    __shared__ float sln[16][256];

    const int tid = threadIdx.x, lane = tid & 63, w = tid >> 6;
    const int m16 = lane & 15, g = lane >> 4;
    const int m0 = blockIdx.x * 16;

    bh8 af[8];
    #pragma unroll
    for (int kq = 0; kq < 8; ++kq)
        af[kq] = af_from_f32(&A[(size_t)(m0 + m16)*256 + kq*32 + g*8]);

    f32x4 acc[2];
    acc[0] = (f32x4){0.f,0.f,0.f,0.f};
    acc[1] = (f32x4){0.f,0.f,0.f,0.f};

    #pragma unroll
    for (int i = 0; i < 2; ++i) {
        const int nt = w*2 + i;
        #pragma unroll
        for (int kq = 0; kq < 8; ++kq) {
            bh8 bf = *reinterpret_cast<const bh8*>(Wimg + (size_t)(nt*8 + kq)*1024 + lane*16);
            acc[i] = __builtin_amdgcn_mfma_f32_16x16x32_bf16(af[kq], bf, acc[i], 0, 0, 0);
        }
    }

    #pragma unroll
    for (int i = 0; i < 2; ++i) {
        const int nt = w*2 + i;
        const int j  = nt*16 + m16;
        #pragma unroll
        for (int r = 0; r < 4; ++r) {
            const int ml = g*4 + r;
            sln[ml][j] = acc[i][r] + bias[j] + res[(size_t)(m0 + ml)*256 + j];
        }
    }
    __syncthreads();

    const int row = tid >> 5, l2 = tid & 31;
    float v[8], s1 = 0.f, s2 = 0.f;
    #pragma unroll
    for (int c = 0; c < 8; ++c) {
        v[c] = sln[row][l2 + c*32];
        s1 += v[c]; s2 += v[c]*v[c];
    }
    #pragma unroll
    for (int o = 16; o >= 1; o >>= 1) {
        s1 += __shfl_xor(s1, o, 64);
        s2 += __shfl_xor(s2, o, 64);
    }
    const float mu  = s1 * (1.f/256.f);
    const float var = s2 * (1.f/256.f) - mu*mu;
    const float is  = rsqrtf(var + 1e-5f);
    #pragma unroll
    for (int c = 0; c < 8; ++c) {
        const int j = l2 + c*32;
        T[(size_t)(m0 + row)*256 + j] = (v[c] - mu) * is * lg[j] + lb[j];
    }
}

// ---------------- fused FFN (f-split 4) ----------------
__global__ __launch_bounds__(512)
void ffn_k(const float* __restrict__ T, const unsigned char* __restrict__ W1img,
           const float* __restrict__ b1, const unsigned char* __restrict__ W2img,
           const float* __restrict__ b2, float* __restrict__ Y)
{
    __shared__ __align__(16) short hl[2][32*72];

    const int tid = threadIdx.x, lane = tid & 63, w = tid >> 6;
    const int m16 = lane & 15, g = lane >> 4;
    const int mt = w & 1, wn = w >> 1;
    const int m0 = blockIdx.x * 32;
    const int fg = blockIdx.y;

    bh8 af1[8];
    #pragma unroll
    for (int kq = 0; kq < 8; ++kq) {
        int gm = m0 + mt*16 + m16; if (gm > MQ_-1) gm = MQ_-1;
        af1[kq] = af_from_f32(&T[(size_t)gm*256 + kq*32 + g*8]);
    }

    f32x4 yacc[4];
    #pragma unroll
    for (int i = 0; i < 4; ++i) yacc[i] = (f32x4){0.f,0.f,0.f,0.f};

    int buf = 0;
    #pragma unroll
    for (int fc = 0; fc < 4; ++fc) {
        const int ftile_g = fg*16 + fc*4 + wn;
        f32x4 hacc = (f32x4){0.f,0.f,0.f,0.f};
        #pragma unroll
        for (int kq = 0; kq < 8; ++kq) {
            bh8 bf = *reinterpret_cast<const bh8*>(W1img + (size_t)(ftile_g*8 + kq)*1024 + lane*16);
            hacc = __builtin_amdgcn_mfma_f32_16x16x32_bf16(af1[kq], bf, hacc, 0, 0, 0);
        }
        const float bb = b1[ftile_g*16 + m16];
        #pragma unroll
        for (int r = 0; r < 4; ++r) {
            const float v = fmaxf(hacc[r] + bb, 0.f);
            *reinterpret_cast<short*>((char*)&hl[buf][0]
                + (mt*16 + g*4 + r)*144 + (wn*16 + m16)*2) = bf16b(v);
        }
        __syncthreads();
        bh8 a2[2];
        #pragma unroll
        for (int kqf = 0; kqf < 2; ++kqf)
            a2[kqf] = *reinterpret_cast<const bh8*>((char*)&hl[buf][0]
                + (mt*16 + m16)*144 + (kqf*32 + g*8)*2);
        #pragma unroll
        for (int i = 0; i < 4; ++i) {
            const int nt = wn*4 + i;
            #pragma unroll
            for (int kqf = 0; kqf < 2; ++kqf) {
                const int kq2 = fg*8 + fc*2 + kqf;
                bh8 bf = *reinterpret_cast<const bh8*>(W2img + (size_t)(nt*32 + kq2)*1024 + lane*16);
                yacc[i] = __builtin_amdgcn_mfma_f32_16x16x32_bf16(a2[kqf], bf, yacc[i], 0, 0, 0);
            }
        }
        buf ^= 1;
    }

    float* Yg = Y + (size_t)fg*MQ_*256;
    #pragma unroll
    for (int i = 0; i < 4; ++i) {
        const int j = (wn*4 + i)*16 + m16;
        const float b2v = (fg == 0) ? b2[j] : 0.f;
        #pragma unroll
        for (int r = 0; r < 4; ++r) {
            const int m = m0 + mt*16 + g*4 + r;
            if (m < MQ_) Yg[(size_t)m*256 + j] = yacc[i][r] + b2v;
        }
    }
}

// ---------------- deformable sampling ----------------
__global__ __launch_bounds__(256)
void msda_k(const float* __restrict__ off,
            const float* __restrict__ attnlog,
            const float* __restrict__ refp,
            const __hip_bfloat16* __restrict__ value,
            float* __restrict__ out)
{
    const int m = blockIdx.x;
    const int b = m & 3;
    const int d = threadIdx.x;
    const int h = d >> 5;

    __shared__ float s_off[256];
    __shared__ float s_al[128];
    __shared__ float s_ref[NL_*2];
    s_off[d] = off[(size_t)m*256 + d];
    if (d < 128) s_al[d] = attnlog[(size_t)m*128 + d];
    if (d < NL_*2) s_ref[d] = refp[(size_t)m*(NL_*2) + d];
    __syncthreads();

    float mx = -1e30f;
    #pragma unroll
    for (int t = 0; t < 16; ++t) mx = fmaxf(mx, s_al[h*16 + t]);
    float e[16], ssum = 0.f;
    #pragma unroll
    for (int t = 0; t < 16; ++t) { e[t] = __expf(s_al[h*16 + t] - mx); ssum += e[t]; }
    const float inv = 1.f / ssum;

    const int HS[4] = {128, 64, 32, 16};
    const int ST[4] = {0, 16384, 20480, 21504};

    float acc = 0.f;
    #pragma unroll
    for (int l = 0; l < NL_; ++l) {
        const int H = HS[l], W = HS[l], st = ST[l];
        const float rx = s_ref[l*2+0], ry = s_ref[l*2+1];
        #pragma unroll
        for (int p = 0; p < NP_; ++p) {
            const int base = ((h*NL_ + l)*NP_ + p);
            const float a  = e[l*4 + p] * inv;
            const float ox = s_off[base*2+0], oy = s_off[base*2+1];
            const float x = rx*(float)W + ox - 0.5f;
            const float y = ry*(float)H + oy - 0.5f;
            const float x0f = floorf(x), y0f = floorf(y);
            const int x0 = (int)x0f, y0 = (int)y0f;
            const float wx1 = x - x0f, wy1 = y - y0f;
            const float wx0 = 1.f - wx1, wy0 = 1.f - wy1;
            #pragma unroll
            for (int t = 0; t < 4; ++t) {
                const int xi = x0 + (t & 1);
                const int yi = y0 + (t >> 1);
                const float wgt = (t==0 ? wx0*wy0 : t==1 ? wx1*wy0 : t==2 ? wx0*wy1 : wx1*wy1);
                if (xi >= 0 && xi < W && yi >= 0 && yi < H) {
                    const size_t idx = (size_t)(st + yi*W + xi);
                    const float v = __bfloat162float(value[(idx*B_ + b)*D_ + d]);
                    acc = fmaf(a*wgt, v, acc);
                }
            }
        }
    }
    out[(size_t)m*256 + d] = acc;
}

// ---- final LN: out = LN(t + y0+y1+y2+y3) ----
__global__ __launch_bounds__(256)
void add_ln4_k(const float* __restrict__ yp, const float* __restrict__ r,
               const float* __restrict__ g, const float* __restrict__ be,
               float* __restrict__ out)
{
    const int m = blockIdx.x, d = threadIdx.x;
    const size_t S = (size_t)MQ_*256, o = (size_t)m*D_ + d;
    const float v = r[o] + yp[o] + yp[S+o] + yp[2*S+o] + yp[3*S+o];
    float s1 = v, s2 = v*v;
    #pragma unroll
    for (int of = 32; of >= 1; of >>= 1) {
        s1 += __shfl_xor(s1, of, 64);
        s2 += __shfl_xor(s2, of, 64);
    }
    __shared__ float r1[4], r2[4];
    const int w = d >> 6;
    if ((d & 63) == 0) { r1[w] = s1; r2[w] = s2; }
    __syncthreads();
    const float t1 = r1[0]+r1[1]+r1[2]+r1[3];
    const float t2 = r2[0]+r2[1]+r2[2]+r2[3];
    const float mu  = t1 * (1.f/D_);
    const float var = t2 * (1.f/D_) - mu*mu;
    const float is  = rsqrtf(var + 1e-5f);
    out[o] = (v - mu) * is * g[d] + be[d];
}

extern "C" void kernel_launch(void* const* d_in, const int* in_sizes, int n_in,
                              void* d_out, int out_size, void* d_ws, size_t ws_size,
                              hipStream_t stream)
{
    const float* tgt    = (const float*)d_in[0];
    const float* refp   = (const float*)d_in[1];
    const float* mem    = (const float*)d_in[2];
    const float* W_off  = (const float*)d_in[3];
    const float* b_off  = (const float*)d_in[4];
    const float* W_attn = (const float*)d_in[5];
    const float* b_attn = (const float*)d_in[6];
    const float* W_val  = (const float*)d_in[7];
    const float* b_val  = (const float*)d_in[8];
    const float* W_out  = (const float*)d_in[9];
    const float* b_out  = (const float*)d_in[10];
    const float* ln1g   = (const float*)d_in[11];
    const float* ln1b   = (const float*)d_in[12];
    const float* W1     = (const float*)d_in[13];
    const float* b1     = (const float*)d_in[14];
    const float* W2     = (const float*)d_in[15];
    const float* b2     = (const float*)d_in[16];
    const float* ln3g   = (const float*)d_in[17];
    const float* ln3b   = (const float*)d_in[18];
    const unsigned char* mask = (const unsigned char*)d_in[21];
    float* out = (float*)d_out;

    char* p = (char*)d_ws;
    __hip_bfloat16* value = (__hip_bfloat16*)p; p += (size_t)MV_*D_*2;   // 44.6 MB
    float* offb = (float*)p; p += (size_t)MQ_*256*4;
    float* attl = (float*)p; p += (size_t)MQ_*128*4;
    float* msda = (float*)p; p += (size_t)MQ_*256*4;
    float* tb   = (float*)p; p += (size_t)MQ_*256*4;
    float* ypart= (float*)p; p += (size_t)4*MQ_*256*4;                   // 14.7 MB
    unsigned char* qkvimg = (unsigned char*)p; p += 196608;
    unsigned char* outimg = (unsigned char*)p; p += 131072;
    unsigned char* w1img  = (unsigned char*)p; p += 524288;
    unsigned char* w2img  = (unsigned char*)p; p += 524288;
    unsigned char* valimg = (unsigned char*)p; p += 131072;
    (void)ws_size; (void)in_sizes; (void)n_in; (void)out_size;

    // 0) weight B-frag images (incl. W_val)
    wprep_k<<<dim3(368), dim3(256), 0, stream>>>(W_off, W_attn, W_out, W1, W2, W_val,
                                                 qkvimg, outimg, w1img, w2img, valimg);
    // 1) value projection: 2-phase pipelined MFMA
    val_gemm_k<<<dim3(MV_/128), dim3(512), 0, stream>>>(mem, valimg, b_val,
                                                        (unsigned short*)value, mask);
    // 2+3) off + attn logits, fused
    qkv_k<<<dim3(MQ_/16), dim3(512), 0, stream>>>(tgt, qkvimg, b_off, b_attn, offb, attl);
    // 4) deformable sampling
    msda_k<<<dim3(MQ_), dim3(256), 0, stream>>>(offb, attl, refp, value, msda);
    // 5+6) ca = msda @ W_out^T + b_out ; tb = LN(tgt + ca)   (fused)
    outln_k<<<dim3(MQ_/16), dim3(512), 0, stream>>>(msda, outimg, b_out, tgt, ln1g, ln1b, tb);
    // 7+8) FFN fused, f-split x4
    ffn_k<<<dim3((MQ_+31)/32, 4), dim3(512), 0, stream>>>(tb, w1img, b1, w2img, b2, ypart);
    // 9) out = LN(t + sum(y-partials))
    add_ln4_k<<<dim3(MQ_), dim3(256), 0, stream>>>(ypart, tb, ln3g, ln3b, out);
}